// Round 4
// baseline (742.807 us; speedup 1.0000x reference)
//
#include <hip/hip_runtime.h>
#include <hip/hip_bf16.h>
#include <math.h>

#define NN 100000
#define CC 128
#define EE 1600000
#define SCAN_CHUNK 2048
#define NB_SCAN ((NN + SCAN_CHUNK - 1) / SCAN_CHUNK)  // 49
#define NRANGE 8
#define RNODES (NN / NRANGE)     // 12500
#define EPT 8                    // edges per thread in fill
#define FCHUNK (256 * EPT)       // 2048 edges per block
#define NCHUNKS ((EE + FCHUNK - 1) / FCHUNK)  // 782

typedef short  bf16x8 __attribute__((ext_vector_type(8)));
typedef float  f32x4  __attribute__((ext_vector_type(4)));
typedef unsigned short u16x8 __attribute__((ext_vector_type(8)));

#define APAD 136   // ushort stride for At rows (272 B, 16B-aligned)
#define TPAD 132   // float stride for Tt rows (528 B, 16B-aligned)

__device__ __forceinline__ ushort f2bf(float f) {
    __hip_bfloat16 h = __float2bfloat16(f);   // RNE
    return __builtin_bit_cast(ushort, h);
}
__device__ __forceinline__ float bf2f(ushort u) {
    return __builtin_bit_cast(float, ((unsigned int)u) << 16);
}

// ===========================================================================
// CSR build
// ===========================================================================
__global__ void __launch_bounds__(256) hist_kernel(
    const int* __restrict__ dst, int* __restrict__ deg)
{
    int e = blockIdx.x * 256 + threadIdx.x;
    if (e < EE) atomicAdd(&deg[dst[e]], 1);
}

__global__ void __launch_bounds__(256) deg_block_reduce(
    const int* __restrict__ deg, int* __restrict__ blockSums)
{
    int base = blockIdx.x * SCAN_CHUNK + threadIdx.x * 8;
    int s = 0;
#pragma unroll
    for (int i = 0; i < 8; ++i) {
        int idx = base + i;
        if (idx < NN) s += deg[idx];
    }
#pragma unroll
    for (int off = 32; off > 0; off >>= 1) s += __shfl_down(s, off);
    __shared__ int ws[4];
    int lane = threadIdx.x & 63, wid = threadIdx.x >> 6;
    if (lane == 0) ws[wid] = s;
    __syncthreads();
    if (threadIdx.x == 0) blockSums[blockIdx.x] = ws[0] + ws[1] + ws[2] + ws[3];
}

__global__ void scan_offsets(const int* __restrict__ blockSums,
                             int* __restrict__ blockOff, int* __restrict__ rowptr)
{
    int lane = threadIdx.x;  // 64 threads
    int v = (lane < NB_SCAN) ? blockSums[lane] : 0;
    int inc = v;
#pragma unroll
    for (int off = 1; off < 64; off <<= 1) {
        int n = __shfl_up(inc, off);
        if (lane >= off) inc += n;
    }
    if (lane < NB_SCAN) blockOff[lane] = inc - v;
    if (lane == 63) rowptr[NN] = EE;
}

__global__ void __launch_bounds__(256) deg_scan_write(
    const int* __restrict__ deg, const int* __restrict__ blockOff,
    int* __restrict__ rowptr, int* __restrict__ cursor)
{
    __shared__ int warpSums[4];
    int base = blockIdx.x * SCAN_CHUNK + threadIdx.x * 8;
    int v[8];
    int s = 0;
#pragma unroll
    for (int i = 0; i < 8; ++i) {
        int idx = base + i;
        v[i] = (idx < NN) ? deg[idx] : 0;
        s += v[i];
    }
    int lane = threadIdx.x & 63, wid = threadIdx.x >> 6;
    int inc = s;
#pragma unroll
    for (int off = 1; off < 64; off <<= 1) {
        int n = __shfl_up(inc, off);
        if (lane >= off) inc += n;
    }
    if (lane == 63) warpSums[wid] = inc;
    __syncthreads();
    int wofs = 0;
#pragma unroll
    for (int w = 0; w < 4; ++w)
        if (w < wid) wofs += warpSums[w];
    int exc = blockOff[blockIdx.x] + wofs + (inc - s);
#pragma unroll
    for (int i = 0; i < 8; ++i) {
        int idx = base + i;
        if (idx < NN) { rowptr[idx] = exc; cursor[idx] = exc; }
        exc += v[i];
    }
}

// XCD-range-partitioned fill: block (b&7) handles dst range [lo,hi).
// With round-robin block->XCD dispatch, each range's col/cursor region is
// written by a single XCD -> full-line L2 writebacks instead of cross-XCD
// partial-line ping-pong. Correctness does NOT depend on the mapping.
__global__ void __launch_bounds__(256) fill_csr_part(
    const int* __restrict__ src, const int* __restrict__ dst,
    int* __restrict__ cursor, int* __restrict__ col)
{
    int range = blockIdx.x & (NRANGE - 1);
    int chunk = blockIdx.x >> 3;
    int lo = range * RNODES, hi = lo + RNODES;
    int base = chunk * FCHUNK + threadIdx.x * EPT;
    if (base + EPT <= EE) {
        int4 d0 = *(const int4*)&dst[base];
        int4 d1 = *(const int4*)&dst[base + 4];
        int dd[8] = {d0.x, d0.y, d0.z, d0.w, d1.x, d1.y, d1.z, d1.w};
#pragma unroll
        for (int i = 0; i < 8; ++i) {
            int d = dd[i];
            if (d >= lo && d < hi) {
                int s = src[base + i];
                int pos = atomicAdd(&cursor[d], 1);
                col[pos] = s;
            }
        }
    } else {
        for (int i = 0; i < EPT; ++i) {
            int e = base + i;
            if (e < EE) {
                int d = dst[e];
                if (d >= lo && d < hi) {
                    int s = src[e];
                    int pos = atomicAdd(&cursor[d], 1);
                    col[pos] = s;
                }
            }
        }
    }
}

// ===========================================================================
// Conversions
// ===========================================================================
__global__ void __launch_bounds__(256) convert_x_kernel(
    const float* __restrict__ x, ushort* __restrict__ xb)
{
    int i = blockIdx.x * 256 + threadIdx.x;   // float4 groups; NN*CC/4 total
    float4 v = ((const float4*)x)[i];
    ushort4 o;
    o.x = f2bf(v.x); o.y = f2bf(v.y); o.z = f2bf(v.z); o.w = f2bf(v.w);
    ((ushort4*)xb)[i] = o;
}

// all 6 weight matrices in one launch: [128][128] fp32 (k,n) -> bf16 (n,k)
__global__ void __launch_bounds__(256) convert_w6_kernel(
    const float* __restrict__ w0, const float* __restrict__ w1,
    const float* __restrict__ w2, const float* __restrict__ w3,
    const float* __restrict__ w4, const float* __restrict__ w5,
    ushort* __restrict__ wt)
{
    int i = blockIdx.x * 256 + threadIdx.x;  // 6*16384
    int mat = i >> 14;
    int rem = i & 16383;
    int k = rem >> 7, n = rem & 127;
    const float* w = (mat == 0) ? w0 : (mat == 1) ? w1 : (mat == 2) ? w2
                   : (mat == 3) ? w3 : (mat == 4) ? w4 : w5;
    wt[mat * 16384 + n * 128 + k] = f2bf(w[k * 128 + n]);
}

// ===========================================================================
// Fused GIN layer: gather(agg = h + sum_nbr h) -> relu GEMM -> elu GEMM
// Block = 256 thr = 4 waves; tile 64 rows x 128 cols; K=128.
// LDS: At (bf16, 17408 B) unioned with Tt (fp32, 33792 B).
// ===========================================================================
template <bool FUSE_HEAD>
__global__ void __launch_bounds__(256) gin_layer(
    const ushort* __restrict__ hin, const int* __restrict__ rowptr,
    const int* __restrict__ col,
    const ushort* __restrict__ waT, const float* __restrict__ ba,
    const ushort* __restrict__ wbT, const float* __restrict__ bb,
    ushort* __restrict__ hout,
    const float* __restrict__ lw, const float* __restrict__ lb,
    float* __restrict__ out)
{
    __shared__ float smem[64 * TPAD];           // 33792 B
    ushort* At = (ushort*)smem;                 // 64*APAD ushorts = 17408 B
    float*  Tt = smem;

    const int tid  = threadIdx.x;
    const int row0 = blockIdx.x * 64;

    // ---- fused gather into At: 16 groups x 16 lanes; 4 nodes per group ----
    {
        const int grp  = tid >> 4;    // 0..15
        const int lane = tid & 15;    // owns channels lane*8..lane*8+7
        const u16x8* hp = (const u16x8*)hin;
#pragma unroll
        for (int i = 0; i < 4; ++i) {
            int r = grp * 4 + i;          // row within tile
            int n = row0 + r;
            float s[8], t[8];
            if (n < NN) {
                u16x8 self = hp[n * 16 + lane];
#pragma unroll
                for (int k = 0; k < 8; ++k) { s[k] = bf2f(self[k]); t[k] = 0.f; }
                int beg = rowptr[n], end = rowptr[n + 1];
                int j = beg;
                for (; j + 1 < end; j += 2) {
                    int n0 = col[j], n1 = col[j + 1];
                    u16x8 a = hp[n0 * 16 + lane];
                    u16x8 b = hp[n1 * 16 + lane];
#pragma unroll
                    for (int k = 0; k < 8; ++k) { s[k] += bf2f(a[k]); t[k] += bf2f(b[k]); }
                }
                if (j < end) {
                    u16x8 a = hp[col[j] * 16 + lane];
#pragma unroll
                    for (int k = 0; k < 8; ++k) s[k] += bf2f(a[k]);
                }
#pragma unroll
                for (int k = 0; k < 8; ++k) s[k] += t[k];
            } else {
#pragma unroll
                for (int k = 0; k < 8; ++k) s[k] = 0.f;
            }
            bf16x8 o;
#pragma unroll
            for (int k = 0; k < 8; ++k) o[k] = (short)f2bf(s[k]);
            *(bf16x8*)&At[r * APAD + lane * 8] = o;
        }
    }
    __syncthreads();   // (1) gather done

    const int wave = tid >> 6;
    const int lane = tid & 63;
    const int m0   = wave * 16;
    const int quad = lane >> 4;
    const int l16  = lane & 15;

    // ---- stage-1 A fragments ----
    bf16x8 afrag[4];
#pragma unroll
    for (int kk = 0; kk < 4; ++kk)
        afrag[kk] = *(const bf16x8*)&At[(m0 + l16) * APAD + kk * 32 + quad * 8];
    __syncthreads();   // (2) all afrag reads done: Tt may overwrite At

    // ---- stage 1: T = relu(A @ Wa + ba) ----
    f32x4 acc[8];
#pragma unroll
    for (int nt = 0; nt < 8; ++nt) acc[nt] = (f32x4){0.f, 0.f, 0.f, 0.f};
#pragma unroll
    for (int kk = 0; kk < 4; ++kk) {
#pragma unroll
        for (int nt = 0; nt < 8; ++nt) {
            bf16x8 bfrag = *(const bf16x8*)&waT[(nt * 16 + l16) * CC + kk * 32 + quad * 8];
            acc[nt] = __builtin_amdgcn_mfma_f32_16x16x32_bf16(afrag[kk], bfrag, acc[nt], 0, 0, 0);
        }
    }
#pragma unroll
    for (int nt = 0; nt < 8; ++nt) {
        int colc = nt * 16 + l16;
        float bias = ba[colc];
#pragma unroll
        for (int r = 0; r < 4; ++r) {
            float v = acc[nt][r] + bias;
            Tt[(m0 + quad * 4 + r) * TPAD + colc] = fmaxf(v, 0.f);
        }
    }
    __syncthreads();   // (3) Tt ready

    // ---- stage 2 A-fragments from Tt (cvt fp32 -> bf16) ----
    bf16x8 a2[4];
#pragma unroll
    for (int kk = 0; kk < 4; ++kk) {
        const float* tp = &Tt[(m0 + l16) * TPAD + kk * 32 + quad * 8];
        float4 t0 = *(const float4*)tp;
        float4 t1 = *(const float4*)(tp + 4);
        bf16x8 f;
        f[0] = (short)f2bf(t0.x); f[1] = (short)f2bf(t0.y);
        f[2] = (short)f2bf(t0.z); f[3] = (short)f2bf(t0.w);
        f[4] = (short)f2bf(t1.x); f[5] = (short)f2bf(t1.y);
        f[6] = (short)f2bf(t1.z); f[7] = (short)f2bf(t1.w);
        a2[kk] = f;
    }
    __syncthreads();   // (4) a2 reads done: epilogue may overwrite Tt

    // ---- stage 2: out = elu(T @ Wb + bb) ----
    f32x4 acc2[8];
#pragma unroll
    for (int nt = 0; nt < 8; ++nt) acc2[nt] = (f32x4){0.f, 0.f, 0.f, 0.f};
#pragma unroll
    for (int kk = 0; kk < 4; ++kk) {
#pragma unroll
        for (int nt = 0; nt < 8; ++nt) {
            bf16x8 bfrag = *(const bf16x8*)&wbT[(nt * 16 + l16) * CC + kk * 32 + quad * 8];
            acc2[nt] = __builtin_amdgcn_mfma_f32_16x16x32_bf16(a2[kk], bfrag, acc2[nt], 0, 0, 0);
        }
    }

    if (FUSE_HEAD) {
        float part[4] = {0.f, 0.f, 0.f, 0.f};
#pragma unroll
        for (int nt = 0; nt < 8; ++nt) {
            int colc = nt * 16 + l16;
            float bias = bb[colc];
            float w = lw[colc];
#pragma unroll
            for (int r = 0; r < 4; ++r) {
                float v = acc2[nt][r] + bias;
                v = v > 0.f ? v : expm1f(v);
                part[r] += v * w;
            }
        }
#pragma unroll
        for (int r = 0; r < 4; ++r) {
#pragma unroll
            for (int off = 8; off > 0; off >>= 1)
                part[r] += __shfl_xor(part[r], off);
        }
        if (l16 == 0) {
            float lbv = lb[0];
#pragma unroll
            for (int r = 0; r < 4; ++r) {
                int grow = row0 + m0 + quad * 4 + r;
                if (grow < NN) {
                    float z = part[r] + lbv;
                    out[grow] = 1.f / (1.f + expf(-z));
                }
            }
        }
    } else {
#pragma unroll
        for (int nt = 0; nt < 8; ++nt) {
            int colc = nt * 16 + l16;
            float bias = bb[colc];
#pragma unroll
            for (int r = 0; r < 4; ++r) {
                float v = acc2[nt][r] + bias;
                Tt[(m0 + quad * 4 + r) * TPAD + colc] = v > 0.f ? v : expm1f(v);
            }
        }
        __syncthreads();   // (5) epilogue Tt ready
#pragma unroll
        for (int i = 0; i < 8; ++i) {
            int v  = tid + i * 256;
            int r  = v >> 5;
            int cv = v & 31;
            int grow = row0 + r;
            if (grow < NN) {
                float4 t = *(const float4*)&Tt[r * TPAD + cv * 4];
                ushort4 o;
                o.x = f2bf(t.x); o.y = f2bf(t.y); o.z = f2bf(t.z); o.w = f2bf(t.w);
                *(ushort4*)&hout[grow * CC + cv * 4] = o;
            }
        }
    }
}

extern "C" void kernel_launch(void* const* d_in, const int* in_sizes, int n_in,
                              void* d_out, int out_size, void* d_ws, size_t ws_size,
                              hipStream_t stream) {
    const float* x   = (const float*)d_in[0];
    const int*   ei  = (const int*)d_in[1];
    const int*   src = ei;
    const int*   dst = ei + EE;
    const float* w0a = (const float*)d_in[2];
    const float* b0a = (const float*)d_in[3];
    const float* w0b = (const float*)d_in[4];
    const float* b0b = (const float*)d_in[5];
    const float* w1a = (const float*)d_in[6];
    const float* b1a = (const float*)d_in[7];
    const float* w1b = (const float*)d_in[8];
    const float* b1b = (const float*)d_in[9];
    const float* w2a = (const float*)d_in[10];
    const float* b2a = (const float*)d_in[11];
    const float* w2b = (const float*)d_in[12];
    const float* b2b = (const float*)d_in[13];
    const float* lw  = (const float*)d_in[14];
    const float* lb  = (const float*)d_in[15];
    float* outp = (float*)d_out;

    // workspace layout
    ushort* xb  = (ushort*)d_ws;                      // N*CC bf16
    ushort* hbA = xb + (size_t)NN * CC;               // N*CC bf16
    ushort* hbB = hbA + (size_t)NN * CC;              // N*CC bf16
    ushort* wT  = hbB + (size_t)NN * CC;              // 6 * 128*128 bf16
    int* col    = (int*)(wT + 6 * CC * CC);           // EE
    int* rowptr    = col + EE;                        // NN+1
    int* cursor    = rowptr + NN + 1;                 // NN
    int* deg       = cursor + NN;                     // NN
    int* blockSums = deg + NN;                        // NB_SCAN
    int* blockOff  = blockSums + NB_SCAN;             // NB_SCAN

    ushort* w0aT = wT;
    ushort* w0bT = wT + 1 * CC * CC;
    ushort* w1aT = wT + 2 * CC * CC;
    ushort* w1bT = wT + 3 * CC * CC;
    ushort* w2aT = wT + 4 * CC * CC;
    ushort* w2bT = wT + 5 * CC * CC;

    const int edgeBlocks = EE / 256;          // 6250
    const int layerBlocks = (NN + 63) / 64;   // 1563
    const int cvtXBlocks = (NN * CC / 4) / 256;

    // ---- conversions ----
    convert_x_kernel<<<cvtXBlocks, 256, 0, stream>>>(x, xb);
    convert_w6_kernel<<<6 * 64, 256, 0, stream>>>(w0a, w0b, w1a, w1b, w2a, w2b, wT);

    // ---- CSR build ----
    hipMemsetAsync(deg, 0, NN * sizeof(int), stream);
    hist_kernel<<<edgeBlocks, 256, 0, stream>>>(dst, deg);
    deg_block_reduce<<<NB_SCAN, 256, 0, stream>>>(deg, blockSums);
    scan_offsets<<<1, 64, 0, stream>>>(blockSums, blockOff, rowptr);
    deg_scan_write<<<NB_SCAN, 256, 0, stream>>>(deg, blockOff, rowptr, cursor);
    fill_csr_part<<<NCHUNKS * NRANGE, 256, 0, stream>>>(src, dst, cursor, col);

    // ---- 3 fused layers (head fused into layer 3) ----
    gin_layer<false><<<layerBlocks, 256, 0, stream>>>(xb, rowptr, col,
        w0aT, b0a, w0bT, b0b, hbA, nullptr, nullptr, nullptr);
    gin_layer<false><<<layerBlocks, 256, 0, stream>>>(hbA, rowptr, col,
        w1aT, b1a, w1bT, b1b, hbB, nullptr, nullptr, nullptr);
    gin_layer<true><<<layerBlocks, 256, 0, stream>>>(hbB, rowptr, col,
        w2aT, b2a, w2bT, b2b, nullptr, lw, lb, outp);
}

// Round 5
// 668.451 us; speedup vs baseline: 1.1112x; 1.1112x over previous
//
#include <hip/hip_runtime.h>
#include <hip/hip_bf16.h>
#include <math.h>

#define NN 100000
#define CC 128
#define EE 1600000
#define SCAN_CHUNK 2048
#define NB_SCAN ((NN + SCAN_CHUNK - 1) / SCAN_CHUNK)  // 49
#define NRANGE 8
#define RNODES (NN / NRANGE)     // 12500
#define EPT 8                    // edges per thread in partitioned edge kernels
#define FCHUNK (256 * EPT)       // 2048 edges per block
#define NCHUNKS ((EE + FCHUNK - 1) / FCHUNK)  // 782

typedef short  bf16x8 __attribute__((ext_vector_type(8)));
typedef float  f32x4  __attribute__((ext_vector_type(4)));
typedef unsigned short u16x8 __attribute__((ext_vector_type(8)));

#define APAD 136   // ushort stride for At rows (272 B, 16B-aligned)
#define TPAD 132   // float stride for Tt rows (528 B, 16B-aligned)

__device__ __forceinline__ ushort f2bf(float f) {
    __hip_bfloat16 h = __float2bfloat16(f);   // RNE
    return __builtin_bit_cast(ushort, h);
}
__device__ __forceinline__ float bf2f(ushort u) {
    return __builtin_bit_cast(float, ((unsigned int)u) << 16);
}

// ===========================================================================
// CSR build
// ===========================================================================
// XCD-range-partitioned histogram: block (b&7) only counts dst in its range,
// so the 4B atomic RMWs stay in one XCD's L2 (no cross-XCD line ping-pong).
__global__ void __launch_bounds__(256) hist_part(
    const int* __restrict__ dst, int* __restrict__ deg)
{
    int range = blockIdx.x & (NRANGE - 1);
    int chunk = blockIdx.x >> 3;
    int lo = range * RNODES, hi = lo + RNODES;
    int base = chunk * FCHUNK + threadIdx.x * EPT;
    if (base + EPT <= EE) {
        int4 d0 = *(const int4*)&dst[base];
        int4 d1 = *(const int4*)&dst[base + 4];
        int dd[8] = {d0.x, d0.y, d0.z, d0.w, d1.x, d1.y, d1.z, d1.w};
#pragma unroll
        for (int i = 0; i < 8; ++i) {
            int d = dd[i];
            if (d >= lo && d < hi) atomicAdd(&deg[d], 1);
        }
    } else {
        for (int i = 0; i < EPT; ++i) {
            int e = base + i;
            if (e < EE) {
                int d = dst[e];
                if (d >= lo && d < hi) atomicAdd(&deg[d], 1);
            }
        }
    }
}

__global__ void __launch_bounds__(256) deg_block_reduce(
    const int* __restrict__ deg, int* __restrict__ blockSums)
{
    int base = blockIdx.x * SCAN_CHUNK + threadIdx.x * 8;
    int s = 0;
#pragma unroll
    for (int i = 0; i < 8; ++i) {
        int idx = base + i;
        if (idx < NN) s += deg[idx];
    }
#pragma unroll
    for (int off = 32; off > 0; off >>= 1) s += __shfl_down(s, off);
    __shared__ int ws[4];
    int lane = threadIdx.x & 63, wid = threadIdx.x >> 6;
    if (lane == 0) ws[wid] = s;
    __syncthreads();
    if (threadIdx.x == 0) blockSums[blockIdx.x] = ws[0] + ws[1] + ws[2] + ws[3];
}

__global__ void scan_offsets(const int* __restrict__ blockSums,
                             int* __restrict__ blockOff, int* __restrict__ rowptr)
{
    int lane = threadIdx.x;  // 64 threads
    int v = (lane < NB_SCAN) ? blockSums[lane] : 0;
    int inc = v;
#pragma unroll
    for (int off = 1; off < 64; off <<= 1) {
        int n = __shfl_up(inc, off);
        if (lane >= off) inc += n;
    }
    if (lane < NB_SCAN) blockOff[lane] = inc - v;
    if (lane == 63) rowptr[NN] = EE;
}

__global__ void __launch_bounds__(256) deg_scan_write(
    const int* __restrict__ deg, const int* __restrict__ blockOff,
    int* __restrict__ rowptr, int* __restrict__ cursor)
{
    __shared__ int warpSums[4];
    int base = blockIdx.x * SCAN_CHUNK + threadIdx.x * 8;
    int v[8];
    int s = 0;
#pragma unroll
    for (int i = 0; i < 8; ++i) {
        int idx = base + i;
        v[i] = (idx < NN) ? deg[idx] : 0;
        s += v[i];
    }
    int lane = threadIdx.x & 63, wid = threadIdx.x >> 6;
    int inc = s;
#pragma unroll
    for (int off = 1; off < 64; off <<= 1) {
        int n = __shfl_up(inc, off);
        if (lane >= off) inc += n;
    }
    if (lane == 63) warpSums[wid] = inc;
    __syncthreads();
    int wofs = 0;
#pragma unroll
    for (int w = 0; w < 4; ++w)
        if (w < wid) wofs += warpSums[w];
    int exc = blockOff[blockIdx.x] + wofs + (inc - s);
#pragma unroll
    for (int i = 0; i < 8; ++i) {
        int idx = base + i;
        if (idx < NN) { rowptr[idx] = exc; cursor[idx] = exc; }
        exc += v[i];
    }
}

// XCD-range-partitioned fill (see hist_part comment).
__global__ void __launch_bounds__(256) fill_csr_part(
    const int* __restrict__ src, const int* __restrict__ dst,
    int* __restrict__ cursor, int* __restrict__ col)
{
    int range = blockIdx.x & (NRANGE - 1);
    int chunk = blockIdx.x >> 3;
    int lo = range * RNODES, hi = lo + RNODES;
    int base = chunk * FCHUNK + threadIdx.x * EPT;
    if (base + EPT <= EE) {
        int4 d0 = *(const int4*)&dst[base];
        int4 d1 = *(const int4*)&dst[base + 4];
        int dd[8] = {d0.x, d0.y, d0.z, d0.w, d1.x, d1.y, d1.z, d1.w};
#pragma unroll
        for (int i = 0; i < 8; ++i) {
            int d = dd[i];
            if (d >= lo && d < hi) {
                int s = src[base + i];
                int pos = atomicAdd(&cursor[d], 1);
                col[pos] = s;
            }
        }
    } else {
        for (int i = 0; i < EPT; ++i) {
            int e = base + i;
            if (e < EE) {
                int d = dst[e];
                if (d >= lo && d < hi) {
                    int s = src[e];
                    int pos = atomicAdd(&cursor[d], 1);
                    col[pos] = s;
                }
            }
        }
    }
}

// ===========================================================================
// Conversions
// ===========================================================================
__global__ void __launch_bounds__(256) convert_x_kernel(
    const float* __restrict__ x, ushort* __restrict__ xb)
{
    int i = blockIdx.x * 256 + threadIdx.x;   // float4 groups; NN*CC/4 total
    float4 v = ((const float4*)x)[i];
    ushort4 o;
    o.x = f2bf(v.x); o.y = f2bf(v.y); o.z = f2bf(v.z); o.w = f2bf(v.w);
    ((ushort4*)xb)[i] = o;
}

// all 6 weight matrices in one launch: [128][128] fp32 (k,n) -> bf16 (n,k)
__global__ void __launch_bounds__(256) convert_w6_kernel(
    const float* __restrict__ w0, const float* __restrict__ w1,
    const float* __restrict__ w2, const float* __restrict__ w3,
    const float* __restrict__ w4, const float* __restrict__ w5,
    ushort* __restrict__ wt)
{
    int i = blockIdx.x * 256 + threadIdx.x;  // 6*16384
    int mat = i >> 14;
    int rem = i & 16383;
    int k = rem >> 7, n = rem & 127;
    const float* w = (mat == 0) ? w0 : (mat == 1) ? w1 : (mat == 2) ? w2
                   : (mat == 3) ? w3 : (mat == 4) ? w4 : w5;
    wt[mat * 16384 + n * 128 + k] = f2bf(w[k * 128 + n]);
}

// ===========================================================================
// Fused GIN layer: gather(agg = h + sum_nbr h) -> relu GEMM -> elu GEMM
// Block = 256 thr = 4 waves; tile 64 rows x 128 cols; K=128.
// Gather: 16-lane groups; col indices prefetched 16-wide + shfl broadcast;
// row loads issued unroll-4 into 4 independent accumulator sets (high MLP).
// ===========================================================================
template <bool FUSE_HEAD>
__global__ void __launch_bounds__(256) gin_layer(
    const ushort* __restrict__ hin, const int* __restrict__ rowptr,
    const int* __restrict__ col,
    const ushort* __restrict__ waT, const float* __restrict__ ba,
    const ushort* __restrict__ wbT, const float* __restrict__ bb,
    ushort* __restrict__ hout,
    const float* __restrict__ lw, const float* __restrict__ lb,
    float* __restrict__ out)
{
    __shared__ float smem[64 * TPAD];           // 33792 B
    ushort* At = (ushort*)smem;                 // 64*APAD ushorts = 17408 B
    float*  Tt = smem;

    const int tid  = threadIdx.x;
    const int row0 = blockIdx.x * 64;

    // ---- fused gather into At ----
    {
        const int grp    = tid >> 4;          // 0..15
        const int lane16 = tid & 15;          // channel chunk owner
        const int wlane  = tid & 63;
        const int gbase  = wlane & 48;        // group base lane within wave
        const u16x8* hp = (const u16x8*)hin;

        const int nbase = row0 + grp * 4;
#pragma unroll
        for (int i = 0; i < 4; ++i) {
            int n = nbase + i;
            float s0[8], s1[8], s2[8], s3[8];
            bool valid = (n < NN);
            if (valid) {
                u16x8 self = hp[n * 16 + lane16];
#pragma unroll
                for (int k = 0; k < 8; ++k) {
                    s0[k] = bf2f(self[k]); s1[k] = 0.f; s2[k] = 0.f; s3[k] = 0.f;
                }
                int beg = rowptr[n], end = rowptr[n + 1];
                while (beg < end) {
                    int take = end - beg;
                    if (take > 16) take = 16;
                    int ci = (lane16 < take) ? col[beg + lane16] : 0;
                    int j = 0;
                    for (; j + 4 <= take; j += 4) {
                        int n0 = __shfl(ci, gbase + j + 0);
                        int n1 = __shfl(ci, gbase + j + 1);
                        int n2 = __shfl(ci, gbase + j + 2);
                        int n3 = __shfl(ci, gbase + j + 3);
                        u16x8 a0 = hp[n0 * 16 + lane16];
                        u16x8 a1 = hp[n1 * 16 + lane16];
                        u16x8 a2 = hp[n2 * 16 + lane16];
                        u16x8 a3 = hp[n3 * 16 + lane16];
#pragma unroll
                        for (int k = 0; k < 8; ++k) {
                            s0[k] += bf2f(a0[k]); s1[k] += bf2f(a1[k]);
                            s2[k] += bf2f(a2[k]); s3[k] += bf2f(a3[k]);
                        }
                    }
                    for (; j < take; ++j) {
                        int n0 = __shfl(ci, gbase + j);
                        u16x8 a0 = hp[n0 * 16 + lane16];
#pragma unroll
                        for (int k = 0; k < 8; ++k) s0[k] += bf2f(a0[k]);
                    }
                    beg += take;
                }
#pragma unroll
                for (int k = 0; k < 8; ++k) s0[k] += s1[k] + s2[k] + s3[k];
            } else {
#pragma unroll
                for (int k = 0; k < 8; ++k) s0[k] = 0.f;
            }
            bf16x8 o;
#pragma unroll
            for (int k = 0; k < 8; ++k) o[k] = (short)f2bf(s0[k]);
            *(bf16x8*)&At[(grp * 4 + i) * APAD + lane16 * 8] = o;
        }
    }
    __syncthreads();   // (1) gather done

    const int wave = tid >> 6;
    const int lane = tid & 63;
    const int m0   = wave * 16;
    const int quad = lane >> 4;
    const int l16  = lane & 15;

    // ---- stage-1 A fragments ----
    bf16x8 afrag[4];
#pragma unroll
    for (int kk = 0; kk < 4; ++kk)
        afrag[kk] = *(const bf16x8*)&At[(m0 + l16) * APAD + kk * 32 + quad * 8];
    __syncthreads();   // (2) all afrag reads done: Tt may overwrite At

    // ---- stage 1: T = relu(A @ Wa + ba) ----
    f32x4 acc[8];
#pragma unroll
    for (int nt = 0; nt < 8; ++nt) acc[nt] = (f32x4){0.f, 0.f, 0.f, 0.f};
#pragma unroll
    for (int kk = 0; kk < 4; ++kk) {
#pragma unroll
        for (int nt = 0; nt < 8; ++nt) {
            bf16x8 bfrag = *(const bf16x8*)&waT[(nt * 16 + l16) * CC + kk * 32 + quad * 8];
            acc[nt] = __builtin_amdgcn_mfma_f32_16x16x32_bf16(afrag[kk], bfrag, acc[nt], 0, 0, 0);
        }
    }
#pragma unroll
    for (int nt = 0; nt < 8; ++nt) {
        int colc = nt * 16 + l16;
        float bias = ba[colc];
#pragma unroll
        for (int r = 0; r < 4; ++r) {
            float v = acc[nt][r] + bias;
            Tt[(m0 + quad * 4 + r) * TPAD + colc] = fmaxf(v, 0.f);
        }
    }
    __syncthreads();   // (3) Tt ready

    // ---- stage 2 A-fragments from Tt (cvt fp32 -> bf16) ----
    bf16x8 a2[4];
#pragma unroll
    for (int kk = 0; kk < 4; ++kk) {
        const float* tp = &Tt[(m0 + l16) * TPAD + kk * 32 + quad * 8];
        float4 t0 = *(const float4*)tp;
        float4 t1 = *(const float4*)(tp + 4);
        bf16x8 f;
        f[0] = (short)f2bf(t0.x); f[1] = (short)f2bf(t0.y);
        f[2] = (short)f2bf(t0.z); f[3] = (short)f2bf(t0.w);
        f[4] = (short)f2bf(t1.x); f[5] = (short)f2bf(t1.y);
        f[6] = (short)f2bf(t1.z); f[7] = (short)f2bf(t1.w);
        a2[kk] = f;
    }
    __syncthreads();   // (4) a2 reads done: epilogue may overwrite Tt

    // ---- stage 2: out = elu(T @ Wb + bb) ----
    f32x4 acc2[8];
#pragma unroll
    for (int nt = 0; nt < 8; ++nt) acc2[nt] = (f32x4){0.f, 0.f, 0.f, 0.f};
#pragma unroll
    for (int kk = 0; kk < 4; ++kk) {
#pragma unroll
        for (int nt = 0; nt < 8; ++nt) {
            bf16x8 bfrag = *(const bf16x8*)&wbT[(nt * 16 + l16) * CC + kk * 32 + quad * 8];
            acc2[nt] = __builtin_amdgcn_mfma_f32_16x16x32_bf16(a2[kk], bfrag, acc2[nt], 0, 0, 0);
        }
    }

    if (FUSE_HEAD) {
        float part[4] = {0.f, 0.f, 0.f, 0.f};
#pragma unroll
        for (int nt = 0; nt < 8; ++nt) {
            int colc = nt * 16 + l16;
            float bias = bb[colc];
            float w = lw[colc];
#pragma unroll
            for (int r = 0; r < 4; ++r) {
                float v = acc2[nt][r] + bias;
                v = v > 0.f ? v : expm1f(v);
                part[r] += v * w;
            }
        }
#pragma unroll
        for (int r = 0; r < 4; ++r) {
#pragma unroll
            for (int off = 8; off > 0; off >>= 1)
                part[r] += __shfl_xor(part[r], off);
        }
        if (l16 == 0) {
            float lbv = lb[0];
#pragma unroll
            for (int r = 0; r < 4; ++r) {
                int grow = row0 + m0 + quad * 4 + r;
                if (grow < NN) {
                    float z = part[r] + lbv;
                    out[grow] = 1.f / (1.f + expf(-z));
                }
            }
        }
    } else {
#pragma unroll
        for (int nt = 0; nt < 8; ++nt) {
            int colc = nt * 16 + l16;
            float bias = bb[colc];
#pragma unroll
            for (int r = 0; r < 4; ++r) {
                float v = acc2[nt][r] + bias;
                Tt[(m0 + quad * 4 + r) * TPAD + colc] = v > 0.f ? v : expm1f(v);
            }
        }
        __syncthreads();   // (5) epilogue Tt ready
#pragma unroll
        for (int i = 0; i < 8; ++i) {
            int v  = tid + i * 256;
            int r  = v >> 5;
            int cv = v & 31;
            int grow = row0 + r;
            if (grow < NN) {
                float4 t = *(const float4*)&Tt[r * TPAD + cv * 4];
                ushort4 o;
                o.x = f2bf(t.x); o.y = f2bf(t.y); o.z = f2bf(t.z); o.w = f2bf(t.w);
                *(ushort4*)&hout[grow * CC + cv * 4] = o;
            }
        }
    }
}

extern "C" void kernel_launch(void* const* d_in, const int* in_sizes, int n_in,
                              void* d_out, int out_size, void* d_ws, size_t ws_size,
                              hipStream_t stream) {
    const float* x   = (const float*)d_in[0];
    const int*   ei  = (const int*)d_in[1];
    const int*   src = ei;
    const int*   dst = ei + EE;
    const float* w0a = (const float*)d_in[2];
    const float* b0a = (const float*)d_in[3];
    const float* w0b = (const float*)d_in[4];
    const float* b0b = (const float*)d_in[5];
    const float* w1a = (const float*)d_in[6];
    const float* b1a = (const float*)d_in[7];
    const float* w1b = (const float*)d_in[8];
    const float* b1b = (const float*)d_in[9];
    const float* w2a = (const float*)d_in[10];
    const float* b2a = (const float*)d_in[11];
    const float* w2b = (const float*)d_in[12];
    const float* b2b = (const float*)d_in[13];
    const float* lw  = (const float*)d_in[14];
    const float* lb  = (const float*)d_in[15];
    float* outp = (float*)d_out;

    // workspace layout
    ushort* xb  = (ushort*)d_ws;                      // N*CC bf16
    ushort* hbA = xb + (size_t)NN * CC;               // N*CC bf16
    ushort* hbB = hbA + (size_t)NN * CC;              // N*CC bf16
    ushort* wT  = hbB + (size_t)NN * CC;              // 6 * 128*128 bf16
    int* col    = (int*)(wT + 6 * CC * CC);           // EE
    int* rowptr    = col + EE;                        // NN+1
    int* cursor    = rowptr + NN + 1;                 // NN
    int* deg       = cursor + NN;                     // NN
    int* blockSums = deg + NN;                        // NB_SCAN
    int* blockOff  = blockSums + NB_SCAN;             // NB_SCAN

    ushort* w0aT = wT;
    ushort* w0bT = wT + 1 * CC * CC;
    ushort* w1aT = wT + 2 * CC * CC;
    ushort* w1bT = wT + 3 * CC * CC;
    ushort* w2aT = wT + 4 * CC * CC;
    ushort* w2bT = wT + 5 * CC * CC;

    const int layerBlocks = (NN + 63) / 64;   // 1563
    const int cvtXBlocks = (NN * CC / 4) / 256;

    // ---- conversions ----
    convert_x_kernel<<<cvtXBlocks, 256, 0, stream>>>(x, xb);
    convert_w6_kernel<<<6 * 64, 256, 0, stream>>>(w0a, w0b, w1a, w1b, w2a, w2b, wT);

    // ---- CSR build ----
    hipMemsetAsync(deg, 0, NN * sizeof(int), stream);
    hist_part<<<NCHUNKS * NRANGE, 256, 0, stream>>>(dst, deg);
    deg_block_reduce<<<NB_SCAN, 256, 0, stream>>>(deg, blockSums);
    scan_offsets<<<1, 64, 0, stream>>>(blockSums, blockOff, rowptr);
    deg_scan_write<<<NB_SCAN, 256, 0, stream>>>(deg, blockOff, rowptr, cursor);
    fill_csr_part<<<NCHUNKS * NRANGE, 256, 0, stream>>>(src, dst, cursor, col);

    // ---- 3 fused layers (head fused into layer 3) ----
    gin_layer<false><<<layerBlocks, 256, 0, stream>>>(xb, rowptr, col,
        w0aT, b0a, w0bT, b0b, hbA, nullptr, nullptr, nullptr);
    gin_layer<false><<<layerBlocks, 256, 0, stream>>>(hbA, rowptr, col,
        w1aT, b1a, w1bT, b1b, hbB, nullptr, nullptr, nullptr);
    gin_layer<true><<<layerBlocks, 256, 0, stream>>>(hbB, rowptr, col,
        w2aT, b2a, w2bT, b2b, nullptr, lw, lb, outp);
}

// Round 6
// 644.574 us; speedup vs baseline: 1.1524x; 1.0370x over previous
//
#include <hip/hip_runtime.h>
#include <hip/hip_bf16.h>
#include <math.h>

#define NN 100000
#define CC 128
#define EE 1600000
#define SCAN_CHUNK 2048
#define NB_SCAN ((NN + SCAN_CHUNK - 1) / SCAN_CHUNK)  // 49
#define NRANGE 8
#define RNODES (NN / NRANGE)     // 12500
#define EPT 8                    // edges per thread in partitioned edge kernels
#define FCHUNK (256 * EPT)       // 2048 edges per block
#define NCHUNKS ((EE + FCHUNK - 1) / FCHUNK)  // 782

typedef short  bf16x8 __attribute__((ext_vector_type(8)));
typedef float  f32x4  __attribute__((ext_vector_type(4)));
typedef unsigned short u16x8 __attribute__((ext_vector_type(8)));

#define APAD 136   // ushort stride for At rows (272 B, 16B-aligned)
#define TPAD 132   // float stride for Tt rows (528 B, 16B-aligned)

__device__ __forceinline__ ushort f2bf(float f) {
    __hip_bfloat16 h = __float2bfloat16(f);   // RNE
    return __builtin_bit_cast(ushort, h);
}
__device__ __forceinline__ float bf2f(ushort u) {
    return __builtin_bit_cast(float, ((unsigned int)u) << 16);
}

// ===========================================================================
// CSR build (dst-partitioned by XCD range to avoid cross-XCD line ping-pong)
// ===========================================================================
__global__ void __launch_bounds__(256) hist_part(
    const int* __restrict__ dst, int* __restrict__ deg)
{
    int range = blockIdx.x & (NRANGE - 1);
    int chunk = blockIdx.x >> 3;
    int lo = range * RNODES, hi = lo + RNODES;
    int base = chunk * FCHUNK + threadIdx.x * EPT;
    if (base + EPT <= EE) {
        int4 d0 = *(const int4*)&dst[base];
        int4 d1 = *(const int4*)&dst[base + 4];
        int dd[8] = {d0.x, d0.y, d0.z, d0.w, d1.x, d1.y, d1.z, d1.w};
#pragma unroll
        for (int i = 0; i < 8; ++i) {
            int d = dd[i];
            if (d >= lo && d < hi) atomicAdd(&deg[d], 1);
        }
    } else {
        for (int i = 0; i < EPT; ++i) {
            int e = base + i;
            if (e < EE) {
                int d = dst[e];
                if (d >= lo && d < hi) atomicAdd(&deg[d], 1);
            }
        }
    }
}

__global__ void __launch_bounds__(256) deg_block_reduce(
    const int* __restrict__ deg, int* __restrict__ blockSums)
{
    int base = blockIdx.x * SCAN_CHUNK + threadIdx.x * 8;
    int s = 0;
#pragma unroll
    for (int i = 0; i < 8; ++i) {
        int idx = base + i;
        if (idx < NN) s += deg[idx];
    }
#pragma unroll
    for (int off = 32; off > 0; off >>= 1) s += __shfl_down(s, off);
    __shared__ int ws[4];
    int lane = threadIdx.x & 63, wid = threadIdx.x >> 6;
    if (lane == 0) ws[wid] = s;
    __syncthreads();
    if (threadIdx.x == 0) blockSums[blockIdx.x] = ws[0] + ws[1] + ws[2] + ws[3];
}

__global__ void scan_offsets(const int* __restrict__ blockSums,
                             int* __restrict__ blockOff, int* __restrict__ rowptr)
{
    int lane = threadIdx.x;  // 64 threads
    int v = (lane < NB_SCAN) ? blockSums[lane] : 0;
    int inc = v;
#pragma unroll
    for (int off = 1; off < 64; off <<= 1) {
        int n = __shfl_up(inc, off);
        if (lane >= off) inc += n;
    }
    if (lane < NB_SCAN) blockOff[lane] = inc - v;
    if (lane == 63) rowptr[NN] = EE;
}

__global__ void __launch_bounds__(256) deg_scan_write(
    const int* __restrict__ deg, const int* __restrict__ blockOff,
    int* __restrict__ rowptr, int* __restrict__ cursor)
{
    __shared__ int warpSums[4];
    int base = blockIdx.x * SCAN_CHUNK + threadIdx.x * 8;
    int v[8];
    int s = 0;
#pragma unroll
    for (int i = 0; i < 8; ++i) {
        int idx = base + i;
        v[i] = (idx < NN) ? deg[idx] : 0;
        s += v[i];
    }
    int lane = threadIdx.x & 63, wid = threadIdx.x >> 6;
    int inc = s;
#pragma unroll
    for (int off = 1; off < 64; off <<= 1) {
        int n = __shfl_up(inc, off);
        if (lane >= off) inc += n;
    }
    if (lane == 63) warpSums[wid] = inc;
    __syncthreads();
    int wofs = 0;
#pragma unroll
    for (int w = 0; w < 4; ++w)
        if (w < wid) wofs += warpSums[w];
    int exc = blockOff[blockIdx.x] + wofs + (inc - s);
#pragma unroll
    for (int i = 0; i < 8; ++i) {
        int idx = base + i;
        if (idx < NN) { rowptr[idx] = exc; cursor[idx] = exc; }
        exc += v[i];
    }
}

__global__ void __launch_bounds__(256) fill_csr_part(
    const int* __restrict__ src, const int* __restrict__ dst,
    int* __restrict__ cursor, int* __restrict__ col)
{
    int range = blockIdx.x & (NRANGE - 1);
    int chunk = blockIdx.x >> 3;
    int lo = range * RNODES, hi = lo + RNODES;
    int base = chunk * FCHUNK + threadIdx.x * EPT;
    if (base + EPT <= EE) {
        int4 d0 = *(const int4*)&dst[base];
        int4 d1 = *(const int4*)&dst[base + 4];
        int dd[8] = {d0.x, d0.y, d0.z, d0.w, d1.x, d1.y, d1.z, d1.w};
#pragma unroll
        for (int i = 0; i < 8; ++i) {
            int d = dd[i];
            if (d >= lo && d < hi) {
                int s = src[base + i];
                int pos = atomicAdd(&cursor[d], 1);
                col[pos] = s;
            }
        }
    } else {
        for (int i = 0; i < EPT; ++i) {
            int e = base + i;
            if (e < EE) {
                int d = dst[e];
                if (d >= lo && d < hi) {
                    int s = src[e];
                    int pos = atomicAdd(&cursor[d], 1);
                    col[pos] = s;
                }
            }
        }
    }
}

// ===========================================================================
// Conversions
// ===========================================================================
__global__ void __launch_bounds__(256) convert_x_kernel(
    const float* __restrict__ x, ushort* __restrict__ xb)
{
    int i = blockIdx.x * 256 + threadIdx.x;   // float4 groups; NN*CC/4 total
    float4 v = ((const float4*)x)[i];
    ushort4 o;
    o.x = f2bf(v.x); o.y = f2bf(v.y); o.z = f2bf(v.z); o.w = f2bf(v.w);
    ((ushort4*)xb)[i] = o;
}

__global__ void __launch_bounds__(256) convert_w6_kernel(
    const float* __restrict__ w0, const float* __restrict__ w1,
    const float* __restrict__ w2, const float* __restrict__ w3,
    const float* __restrict__ w4, const float* __restrict__ w5,
    ushort* __restrict__ wt)
{
    int i = blockIdx.x * 256 + threadIdx.x;  // 6*16384
    int mat = i >> 14;
    int rem = i & 16383;
    int k = rem >> 7, n = rem & 127;
    const float* w = (mat == 0) ? w0 : (mat == 1) ? w1 : (mat == 2) ? w2
                   : (mat == 3) ? w3 : (mat == 4) ? w4 : w5;
    wt[mat * 16384 + n * 128 + k] = f2bf(w[k * 128 + n]);
}

// ===========================================================================
// Standalone max-occupancy gather: agg[n] = h[n] + sum_nbr h[nbr]  (bf16)
// 16 lanes/node, 16 nodes/block, no LDS. Col indices loaded 16-wide and
// broadcast via shfl; row loads unroll-4 into independent accumulators.
// 6250 blocks -> deep per-CU queue; low VGPR -> 8 waves/SIMD.
// ===========================================================================
__global__ void __launch_bounds__(256) gather_agg(
    const ushort* __restrict__ hin, const int* __restrict__ rowptr,
    const int* __restrict__ col, ushort* __restrict__ agg)
{
    const int grp    = threadIdx.x >> 4;            // 0..15
    const int lane16 = threadIdx.x & 15;
    const int gbase  = (threadIdx.x & 63) & 48;     // group base lane in wave
    const int n = blockIdx.x * 16 + grp;            // 6250*16 = 100000 exact
    const u16x8* hp = (const u16x8*)hin;

    u16x8 self = hp[n * 16 + lane16];
    float s0[8], s1[8], s2[8], s3[8];
#pragma unroll
    for (int k = 0; k < 8; ++k) {
        s0[k] = bf2f(self[k]); s1[k] = 0.f; s2[k] = 0.f; s3[k] = 0.f;
    }

    int beg = rowptr[n], end = rowptr[n + 1];
    while (beg < end) {
        int take = end - beg;
        if (take > 16) take = 16;
        int ci = (lane16 < take) ? col[beg + lane16] : 0;
        int j = 0;
        for (; j + 4 <= take; j += 4) {
            int n0 = __shfl(ci, gbase + j + 0);
            int n1 = __shfl(ci, gbase + j + 1);
            int n2 = __shfl(ci, gbase + j + 2);
            int n3 = __shfl(ci, gbase + j + 3);
            u16x8 a0 = hp[n0 * 16 + lane16];
            u16x8 a1 = hp[n1 * 16 + lane16];
            u16x8 a2 = hp[n2 * 16 + lane16];
            u16x8 a3 = hp[n3 * 16 + lane16];
#pragma unroll
            for (int k = 0; k < 8; ++k) {
                s0[k] += bf2f(a0[k]); s1[k] += bf2f(a1[k]);
                s2[k] += bf2f(a2[k]); s3[k] += bf2f(a3[k]);
            }
        }
        for (; j < take; ++j) {
            int n0 = __shfl(ci, gbase + j);
            u16x8 a0 = hp[n0 * 16 + lane16];
#pragma unroll
            for (int k = 0; k < 8; ++k) s0[k] += bf2f(a0[k]);
        }
        beg += take;
    }

    bf16x8 o;
#pragma unroll
    for (int k = 0; k < 8; ++k) o[k] = (short)f2bf(s0[k] + s1[k] + s2[k] + s3[k]);
    *(bf16x8*)&((ushort*)agg)[n * CC + lane16 * 8] = o;
}

// ===========================================================================
// Dense MFMA MLP: hout = elu( relu( hin @ Wa + ba ) @ Wb + bb )
// Block = 256 thr = 4 waves; tile 64 rows x 128 cols; K=128.
// LDS: At (bf16) unioned with Tt (fp32) = 33792 B -> 4 blocks/CU.
// ===========================================================================
template <bool FUSE_HEAD>
__global__ void __launch_bounds__(256) mlp_mfma(
    const ushort* __restrict__ hin,
    const ushort* __restrict__ waT, const float* __restrict__ ba,
    const ushort* __restrict__ wbT, const float* __restrict__ bb,
    ushort* __restrict__ hout,
    const float* __restrict__ lw, const float* __restrict__ lb,
    float* __restrict__ out)
{
    __shared__ float smem[64 * TPAD];           // 33792 B
    ushort* At = (ushort*)smem;                 // 64*APAD ushorts
    float*  Tt = smem;

    const int tid  = threadIdx.x;
    const int row0 = blockIdx.x * 64;

    // ---- stage A tile: 64 rows x 128 bf16, 16B loads ----
#pragma unroll
    for (int i = 0; i < 4; ++i) {
        int v  = tid + i * 256;
        int r  = v >> 4;        // 0..63
        int kv = v & 15;
        int grow = row0 + r;
        bf16x8 val = {0, 0, 0, 0, 0, 0, 0, 0};
        if (grow < NN) val = *(const bf16x8*)&hin[grow * CC + kv * 8];
        *(bf16x8*)&At[r * APAD + kv * 8] = val;
    }
    __syncthreads();   // (1) At ready

    const int wave = tid >> 6;
    const int lane = tid & 63;
    const int m0   = wave * 16;
    const int quad = lane >> 4;
    const int l16  = lane & 15;

    bf16x8 afrag[4];
#pragma unroll
    for (int kk = 0; kk < 4; ++kk)
        afrag[kk] = *(const bf16x8*)&At[(m0 + l16) * APAD + kk * 32 + quad * 8];
    __syncthreads();   // (2) afrag reads done: Tt may overwrite At

    // ---- stage 1: T = relu(A @ Wa + ba) ----
    f32x4 acc[8];
#pragma unroll
    for (int nt = 0; nt < 8; ++nt) acc[nt] = (f32x4){0.f, 0.f, 0.f, 0.f};
#pragma unroll
    for (int kk = 0; kk < 4; ++kk) {
#pragma unroll
        for (int nt = 0; nt < 8; ++nt) {
            bf16x8 bfrag = *(const bf16x8*)&waT[(nt * 16 + l16) * CC + kk * 32 + quad * 8];
            acc[nt] = __builtin_amdgcn_mfma_f32_16x16x32_bf16(afrag[kk], bfrag, acc[nt], 0, 0, 0);
        }
    }
#pragma unroll
    for (int nt = 0; nt < 8; ++nt) {
        int colc = nt * 16 + l16;
        float bias = ba[colc];
#pragma unroll
        for (int r = 0; r < 4; ++r) {
            float v = acc[nt][r] + bias;
            Tt[(m0 + quad * 4 + r) * TPAD + colc] = fmaxf(v, 0.f);
        }
    }
    __syncthreads();   // (3) Tt ready

    bf16x8 a2[4];
#pragma unroll
    for (int kk = 0; kk < 4; ++kk) {
        const float* tp = &Tt[(m0 + l16) * TPAD + kk * 32 + quad * 8];
        float4 t0 = *(const float4*)tp;
        float4 t1 = *(const float4*)(tp + 4);
        bf16x8 f;
        f[0] = (short)f2bf(t0.x); f[1] = (short)f2bf(t0.y);
        f[2] = (short)f2bf(t0.z); f[3] = (short)f2bf(t0.w);
        f[4] = (short)f2bf(t1.x); f[5] = (short)f2bf(t1.y);
        f[6] = (short)f2bf(t1.z); f[7] = (short)f2bf(t1.w);
        a2[kk] = f;
    }
    __syncthreads();   // (4) a2 reads done: epilogue may overwrite Tt

    // ---- stage 2: out = elu(T @ Wb + bb) ----
    f32x4 acc2[8];
#pragma unroll
    for (int nt = 0; nt < 8; ++nt) acc2[nt] = (f32x4){0.f, 0.f, 0.f, 0.f};
#pragma unroll
    for (int kk = 0; kk < 4; ++kk) {
#pragma unroll
        for (int nt = 0; nt < 8; ++nt) {
            bf16x8 bfrag = *(const bf16x8*)&wbT[(nt * 16 + l16) * CC + kk * 32 + quad * 8];
            acc2[nt] = __builtin_amdgcn_mfma_f32_16x16x32_bf16(a2[kk], bfrag, acc2[nt], 0, 0, 0);
        }
    }

    if (FUSE_HEAD) {
        float part[4] = {0.f, 0.f, 0.f, 0.f};
#pragma unroll
        for (int nt = 0; nt < 8; ++nt) {
            int colc = nt * 16 + l16;
            float bias = bb[colc];
            float w = lw[colc];
#pragma unroll
            for (int r = 0; r < 4; ++r) {
                float v = acc2[nt][r] + bias;
                v = v > 0.f ? v : expm1f(v);
                part[r] += v * w;
            }
        }
#pragma unroll
        for (int r = 0; r < 4; ++r) {
#pragma unroll
            for (int off = 8; off > 0; off >>= 1)
                part[r] += __shfl_xor(part[r], off);
        }
        if (l16 == 0) {
            float lbv = lb[0];
#pragma unroll
            for (int r = 0; r < 4; ++r) {
                int grow = row0 + m0 + quad * 4 + r;
                if (grow < NN) {
                    float z = part[r] + lbv;
                    out[grow] = 1.f / (1.f + expf(-z));
                }
            }
        }
    } else {
#pragma unroll
        for (int nt = 0; nt < 8; ++nt) {
            int colc = nt * 16 + l16;
            float bias = bb[colc];
#pragma unroll
            for (int r = 0; r < 4; ++r) {
                float v = acc2[nt][r] + bias;
                Tt[(m0 + quad * 4 + r) * TPAD + colc] = v > 0.f ? v : expm1f(v);
            }
        }
        __syncthreads();   // (5) epilogue Tt ready
#pragma unroll
        for (int i = 0; i < 8; ++i) {
            int v  = tid + i * 256;
            int r  = v >> 5;
            int cv = v & 31;
            int grow = row0 + r;
            if (grow < NN) {
                float4 t = *(const float4*)&Tt[r * TPAD + cv * 4];
                ushort4 o;
                o.x = f2bf(t.x); o.y = f2bf(t.y); o.z = f2bf(t.z); o.w = f2bf(t.w);
                *(ushort4*)&hout[grow * CC + cv * 4] = o;
            }
        }
    }
}

extern "C" void kernel_launch(void* const* d_in, const int* in_sizes, int n_in,
                              void* d_out, int out_size, void* d_ws, size_t ws_size,
                              hipStream_t stream) {
    const float* x   = (const float*)d_in[0];
    const int*   ei  = (const int*)d_in[1];
    const int*   src = ei;
    const int*   dst = ei + EE;
    const float* w0a = (const float*)d_in[2];
    const float* b0a = (const float*)d_in[3];
    const float* w0b = (const float*)d_in[4];
    const float* b0b = (const float*)d_in[5];
    const float* w1a = (const float*)d_in[6];
    const float* b1a = (const float*)d_in[7];
    const float* w1b = (const float*)d_in[8];
    const float* b1b = (const float*)d_in[9];
    const float* w2a = (const float*)d_in[10];
    const float* b2a = (const float*)d_in[11];
    const float* w2b = (const float*)d_in[12];
    const float* b2b = (const float*)d_in[13];
    const float* lw  = (const float*)d_in[14];
    const float* lb  = (const float*)d_in[15];
    float* outp = (float*)d_out;

    // workspace layout
    ushort* xb  = (ushort*)d_ws;                      // N*CC bf16
    ushort* hbA = xb + (size_t)NN * CC;               // N*CC bf16
    ushort* hbB = hbA + (size_t)NN * CC;              // N*CC bf16
    ushort* agg = hbB + (size_t)NN * CC;              // N*CC bf16
    ushort* wT  = agg + (size_t)NN * CC;              // 6 * 128*128 bf16
    int* col    = (int*)(wT + 6 * CC * CC);           // EE
    int* rowptr    = col + EE;                        // NN+1
    int* cursor    = rowptr + NN + 1;                 // NN
    int* deg       = cursor + NN;                     // NN
    int* blockSums = deg + NN;                        // NB_SCAN
    int* blockOff  = blockSums + NB_SCAN;             // NB_SCAN

    ushort* w0aT = wT;
    ushort* w0bT = wT + 1 * CC * CC;
    ushort* w1aT = wT + 2 * CC * CC;
    ushort* w1bT = wT + 3 * CC * CC;
    ushort* w2aT = wT + 4 * CC * CC;
    ushort* w2bT = wT + 5 * CC * CC;

    const int gatherBlocks = NN / 16;          // 6250
    const int mlpBlocks    = (NN + 63) / 64;   // 1563
    const int cvtXBlocks   = (NN * CC / 4) / 256;

    // ---- conversions ----
    convert_x_kernel<<<cvtXBlocks, 256, 0, stream>>>(x, xb);
    convert_w6_kernel<<<6 * 64, 256, 0, stream>>>(w0a, w0b, w1a, w1b, w2a, w2b, wT);

    // ---- CSR build ----
    hipMemsetAsync(deg, 0, NN * sizeof(int), stream);
    hist_part<<<NCHUNKS * NRANGE, 256, 0, stream>>>(dst, deg);
    deg_block_reduce<<<NB_SCAN, 256, 0, stream>>>(deg, blockSums);
    scan_offsets<<<1, 64, 0, stream>>>(blockSums, blockOff, rowptr);
    deg_scan_write<<<NB_SCAN, 256, 0, stream>>>(deg, blockOff, rowptr, cursor);
    fill_csr_part<<<NCHUNKS * NRANGE, 256, 0, stream>>>(src, dst, cursor, col);

    // ---- layer 1 ----
    gather_agg<<<gatherBlocks, 256, 0, stream>>>(xb, rowptr, col, agg);
    mlp_mfma<false><<<mlpBlocks, 256, 0, stream>>>(agg, w0aT, b0a, w0bT, b0b, hbA,
                                                   nullptr, nullptr, nullptr);
    // ---- layer 2 ----
    gather_agg<<<gatherBlocks, 256, 0, stream>>>(hbA, rowptr, col, agg);
    mlp_mfma<false><<<mlpBlocks, 256, 0, stream>>>(agg, w1aT, b1a, w1bT, b1b, hbB,
                                                   nullptr, nullptr, nullptr);
    // ---- layer 3 + fused head ----
    gather_agg<<<gatherBlocks, 256, 0, stream>>>(hbB, rowptr, col, agg);
    mlp_mfma<true><<<mlpBlocks, 256, 0, stream>>>(agg, w2aT, b2a, w2bT, b2b, nullptr,
                                                  lw, lb, outp);
}